// Round 17
// baseline (204.814 us; speedup 1.0000x reference)
//
#include <hip/hip_runtime.h>
#include <hip/hip_bf16.h>
#include <cstdint>
#include <cstddef>

// ---------------------------------------------------------------- constants
#define IN_CH   128
#define OUT_CH  64
#define CAT_CH  192   // IN_CH + OUT_CH
#define ALD     56    // As row stride (ushorts): 112B = 7x16B
#define BLD     40    // Bs row stride (ushorts): 80B = 5x16B

typedef short bf16x8 __attribute__((ext_vector_type(8)));
typedef float f32x4  __attribute__((ext_vector_type(4)));
typedef float f32x2  __attribute__((ext_vector_type(2)));
typedef int   i32x4  __attribute__((ext_vector_type(4)));
typedef unsigned long long u64;
typedef unsigned int u32;

__device__ __forceinline__ float sigmoidf_(float x) { return 1.f / (1.f + __expf(-x)); }

// fp32 -> bf16 (RNE)
__device__ __forceinline__ unsigned short f2bf(float f) {
    u32 u = __float_as_uint(f);
    u32 r = (u + 0x7fffu + ((u >> 16) & 1u)) >> 16;
    return (unsigned short)r;
}
__device__ __forceinline__ u32 pk2bf(float a, float b) {
    return (u32)f2bf(a) | ((u32)f2bf(b) << 16);
}
__device__ __forceinline__ float bflo(u32 v) { return __uint_as_float(v << 16); }
__device__ __forceinline__ float bfhi(u32 v) { return __uint_as_float(v & 0xffff0000u); }

// fp8 OCP e4m3 (gfx950 native converts)
__device__ __forceinline__ unsigned char f2e4m3(float f) {
    u32 p = __builtin_amdgcn_cvt_pk_fp8_f32(f, f, 0, false);
    return (unsigned char)p;
}
template <bool HI>
__device__ __forceinline__ f32x2 fp8pk(u32 v) {
    return __builtin_amdgcn_cvt_pk_f32_fp8((int)v, HI);
}

// physical XCD id of the executing wave (gfx940+: HW_REG_XCC_ID, 0..7)
__device__ __forceinline__ u32 xcc_id() {
    u32 v;
    asm("s_getreg_b32 %0, hwreg(HW_REG_XCC_ID)" : "=s"(v));
    return v & 7u;
}

// single-use streams: evict-first loads/stores so they don't flush reused tables
__device__ __forceinline__ int ntl_i32(const int* p)        { return __builtin_nontemporal_load(p); }
__device__ __forceinline__ long long ntl_i64(const long long* p) { return __builtin_nontemporal_load(p); }
__device__ __forceinline__ float ntl_f32(const float* p)    { return __builtin_nontemporal_load(p); }
__device__ __forceinline__ u32  ntl_u32(const u32* p)       { return __builtin_nontemporal_load(p); }
__device__ __forceinline__ u64  ntl_u64(const u64* p)       { return __builtin_nontemporal_load(p); }
__device__ __forceinline__ f32x4 ntl_f32x4(const float* p)  { return __builtin_nontemporal_load((const f32x4*)p); }
__device__ __forceinline__ i32x4 ntl_i32x4(const void* p)   { return __builtin_nontemporal_load((const i32x4*)p); }

__device__ __forceinline__ int load_col_nt(const void* ei, int i, int E, int f) {
    return f ? ntl_i32((const int*)ei + E + i) : (int)ntl_i64((const long long*)ei + E + i);
}
__device__ __forceinline__ int load_row_nt(const void* ei, int i, int E, int f) {
    return f ? ntl_i32((const int*)ei + i) : (int)ntl_i64((const long long*)ei + i);
}

// ---------------------------------------------------------------- prep (fused)
__global__ void prep_kernel(int4* __restrict__ zdst, int n16,
                            const unsigned int* __restrict__ ei, int* __restrict__ flag,
                            const float* __restrict__ Wz, const float* __restrict__ Wr,
                            const float* __restrict__ Wh,
                            unsigned short* __restrict__ Bzrt, unsigned short* __restrict__ Wht,
                            int gZ) {
    int b = blockIdx.x, t = threadIdx.x;
    if (b < gZ) {
        int i = b * 256 + t;
        if (i < n16) zdst[i] = make_int4(0, 0, 0, 0);
    } else if (b == gZ) {
        if (t < 64) {
            unsigned int v = ei[(t << 1) + 1];
            unsigned long long bl = __ballot(v != 0u);
            if (t == 0) *flag = (bl != 0ull) ? 1 : 0;   // 1 => int32 layout
        }
    } else {
        int i = (b - gZ - 1) * 256 + t;
        if (i < 192 * CAT_CH) {
            int col = i / CAT_CH, k = i % CAT_CH;
            if (col < 128) {
                float v = (col < 64) ? Wz[k * 64 + col] : Wr[k * 64 + (col - 64)];
                Bzrt[col * CAT_CH + k] = f2bf(v);
            } else {
                Wht[(col - 128) * CAT_CH + k] = f2bf(Wh[k * 64 + (col - 128)]);
            }
        }
    }
}

// ---------------------------------------------------------------- GEMM body (device)
// C[128 rows][TN] = [A0(fp32)|A1] tile @ Bt[col][bOff..bOff+K), k-major bf16.
// B staged per-32-k step into Bs[TN][BLD]; A loads and C stores are
// nontemporal (single-use streams). OUT: 0=bf16, 1=fp8, 2=fp32.
template <int TN, int OUT, bool A1F32>
__device__ __forceinline__ void gemm_body(
    unsigned short* __restrict__ As /*[128][ALD]*/,
    unsigned short* __restrict__ Bs /*[TN][BLD]*/,
    int blk, const float* __restrict__ A0, int a0w,
    const void* __restrict__ A1, int a1w,
    const unsigned short* __restrict__ Bt, int bOff, int K,
    const float* __restrict__ Cacc, void* __restrict__ Cout, int nrows)
{
    const int t = threadIdx.x, lane = t & 63, wave = t >> 6;
    const int rowBase = blk * 128;

    f32x4 acc[2][TN / 16];
#pragma unroll
    for (int rf = 0; rf < 2; rf++)
#pragma unroll
        for (int cf = 0; cf < TN / 16; cf++) acc[rf][cf] = (f32x4){0.f, 0.f, 0.f, 0.f};

    const int srow = t >> 1, half = t & 1;     // A staging: 2 threads/row, 16 k each
    int arow = rowBase + srow;
    if (arow >= nrows) arow = nrows - 1;

    for (int k0 = 0; k0 < K; k0 += 32) {
        __syncthreads();
        {   // stage A chunk (128 rows x 32 k)
            int kk = k0 + half * 16;           // 16-aligned; never straddles a0w
            u32 pk[8];
            if (kk < a0w) {                    // A0: fp32 -> bf16 on the fly
                const float* src = A0 + (size_t)arow * a0w + kk;
#pragma unroll
                for (int q = 0; q < 4; q++) {
                    f32x4 v = ntl_f32x4(src + q * 4);
                    pk[q * 2]     = pk2bf(v[0], v[1]);
                    pk[q * 2 + 1] = pk2bf(v[2], v[3]);
                }
            } else if (A1F32) {
                const float* src = (const float*)A1 + (size_t)arow * a1w + (kk - a0w);
#pragma unroll
                for (int q = 0; q < 4; q++) {
                    f32x4 v = ntl_f32x4(src + q * 4);
                    pk[q * 2]     = pk2bf(v[0], v[1]);
                    pk[q * 2 + 1] = pk2bf(v[2], v[3]);
                }
            } else {                           // A1 already bf16
                const unsigned short* src =
                    (const unsigned short*)A1 + (size_t)arow * a1w + (kk - a0w);
                i32x4 v0 = ntl_i32x4(src);
                i32x4 v1 = ntl_i32x4(src + 8);
                pk[0] = v0[0]; pk[1] = v0[1]; pk[2] = v0[2]; pk[3] = v0[3];
                pk[4] = v1[0]; pk[5] = v1[1]; pk[6] = v1[2]; pk[7] = v1[3];
            }
            *(int4*)&As[srow * ALD + half * 16]     = make_int4(pk[0], pk[1], pk[2], pk[3]);
            *(int4*)&As[srow * ALD + half * 16 + 8] = make_int4(pk[4], pk[5], pk[6], pk[7]);
        }
        // stage B tile (TN cols x 32 k), 16B chunks; B is reused -> normal loads
#pragma unroll
        for (int idx = t * 8; idx < TN * 32; idx += 256 * 8) {
            int col = idx >> 5, kk = idx & 31;
            *(int4*)&Bs[col * BLD + kk] =
                *(const int4*)&Bt[(size_t)col * CAT_CH + bOff + k0 + kk];
        }
        __syncthreads();

        const int rbase = wave * 32;
        const int koff = (lane >> 4) * 8;
        bf16x8 a0 = *(const bf16x8*)&As[(rbase + (lane & 15)) * ALD + koff];
        bf16x8 a1 = *(const bf16x8*)&As[(rbase + 16 + (lane & 15)) * ALD + koff];
#pragma unroll
        for (int cf = 0; cf < TN / 16; cf++) {
            bf16x8 b = *(const bf16x8*)&Bs[(cf * 16 + (lane & 15)) * BLD + koff];
            acc[0][cf] = __builtin_amdgcn_mfma_f32_16x16x32_bf16(a0, b, acc[0][cf], 0, 0, 0);
            acc[1][cf] = __builtin_amdgcn_mfma_f32_16x16x32_bf16(a1, b, acc[1][cf], 0, 0, 0);
        }
    }

#pragma unroll
    for (int rf = 0; rf < 2; rf++)
#pragma unroll
        for (int cf = 0; cf < TN / 16; cf++) {
            int row0 = rowBase + wave * 32 + rf * 16 + (lane >> 4) * 4;
            int col  = cf * 16 + (lane & 15);
#pragma unroll
            for (int r = 0; r < 4; r++) {
                int row = row0 + r;
                if (row < nrows) {
                    float v = acc[rf][cf][r];
                    if (Cacc) v += ntl_f32(&Cacc[(size_t)row * TN + col]);
                    if (OUT == 1)
                        __builtin_nontemporal_store(f2e4m3(v),
                            (unsigned char*)Cout + (size_t)row * TN + col);
                    else if (OUT == 2)
                        __builtin_nontemporal_store(v,
                            (float*)Cout + (size_t)row * TN + col);
                    else
                        ((unsigned short*)Cout)[(size_t)row * TN + col] = f2bf(v);
                }
            }
        }
}

// ---------------------------------------------------------------- work1 (fused)
// Role-interleaved: for blk < 3*gM, role = blk%3 (0: GEMM1, 1: GEMM2a, 2: hist);
// beyond, all hist. Hist shards by PHYSICAL XCD (HW_REG_XCC_ID) with
// workgroup-scope atomics (execute in local XCD L2); GEMM streams are
// nontemporal so they don't evict the 400KB/XCD shard table.
__global__ __launch_bounds__(256) void work1_kernel(
    const float* __restrict__ x, const float* __restrict__ hidden,
    const unsigned short* __restrict__ Bzrt, const unsigned short* __restrict__ Wht,
    unsigned char* __restrict__ Hzr8, float* __restrict__ Hh32,
    const void* __restrict__ ei, const float* __restrict__ ew,
    u64* __restrict__ packed8, u32* __restrict__ rank,
    const int* __restrict__ flag, int E, int N, int gM)
{
    __shared__ unsigned short As[128 * ALD];
    __shared__ unsigned short Bs[128 * BLD];

    const int blk = blockIdx.x;
    int role, idx;
    if (blk < 3 * gM) { role = blk % 3; idx = blk / 3; }
    else              { role = 2;       idx = gM + (blk - 3 * gM); }

    if (role == 0) {
        // GEMM1: Hzr8(fp8) = [x|hidden] @ Bzrt, K=192
        gemm_body<128, 1, true>(As, Bs, idx, x, 128, (const void*)hidden, 64,
                                Bzrt, 0, 192, nullptr, (void*)Hzr8, N);
    } else if (role == 1) {
        // GEMM2a: Hh32(fp32) = x @ Wht[:, 0:128), K=128
        gemm_body<64, 2, false>(As, Bs, idx, x, 128, nullptr, 0,
                                Wht, 0, 128, nullptr, (void*)Hh32, N);
    } else {
        // hist: XCD-local packed histogram, 4 edges/thread, nontemporal streams
        int i0 = (idx * 256 + threadIdx.x) * 4;
        if (i0 >= E) return;
        const u32 shard = xcc_id();
        u64* __restrict__ shp = packed8 + (size_t)shard * N;
        int f = *flag;
        u32 rk[4];
#pragma unroll
        for (int k = 0; k < 4; k++) {
            int i = i0 + k;
            if (i < E) {
                int c = load_col_nt(ei, i, E, f);
                u32 wq = __float2uint_rn(ntl_f32(&ew[i]) * 1048576.0f);  // 2^20 scale
                u64 old = __hip_atomic_fetch_add(&shp[c], (1ull << 32) | (u64)wq,
                                                 __ATOMIC_RELAXED,
                                                 __HIP_MEMORY_SCOPE_WORKGROUP);
                rk[k] = (shard << 28) | (u32)(old >> 32);
            }
        }
#pragma unroll
        for (int k = 0; k < 4; k++)
            if (i0 + k < E) __builtin_nontemporal_store(rk[k], &rank[i0 + k]);
    }
}

// ---------------------------------------------------------------- GEMM2b
// Hhb(bf16) = bf16( Hh32 + RHb @ Wht[:, 128:192) ), K=64
__global__ __launch_bounds__(256) void gemm2b_kernel(
    const unsigned short* __restrict__ RHb, const unsigned short* __restrict__ Wht,
    const float* __restrict__ Hh32, unsigned short* __restrict__ Hhb, int N)
{
    __shared__ unsigned short As[128 * ALD];
    __shared__ unsigned short Bs[64 * BLD];
    gemm_body<64, 0, false>(As, Bs, blockIdx.x, nullptr, 0, (const void*)RHb, 64,
                            Wht, 128, 64, Hh32, (void*)Hhb, N);
}

// ---------------------------------------------------------------- scan (2-phase)
__global__ __launch_bounds__(256) void scan1_kernel(const u64* __restrict__ packed8,
                                                    float* __restrict__ dinv,
                                                    u32* __restrict__ shoff,
                                                    int* __restrict__ starts,
                                                    int* __restrict__ bsum, int n) {
    __shared__ int s[256];
    int i = blockIdx.x * 256 + threadIdx.x;
    int v = 0;
    if (i < n) {
        u32 run = 0, wsum = 0;
#pragma unroll
        for (int sh = 0; sh < 8; sh++) {
            u64 p = packed8[(size_t)sh * n + i];
            shoff[(size_t)sh * n + i] = run;
            run  += (u32)(p >> 32);
            wsum += (u32)p;
        }
        float ws = (float)wsum * (1.0f / 1048576.0f);
        dinv[i] = rsqrtf(1.0f + ws);                 // self-loop weight 1 => deg >= 1
        v = (int)run;
    }
    s[threadIdx.x] = v;
    __syncthreads();
#pragma unroll
    for (int d = 1; d < 256; d <<= 1) {
        int t = (threadIdx.x >= d) ? s[threadIdx.x - d] : 0;
        __syncthreads();
        s[threadIdx.x] += t;
        __syncthreads();
    }
    if (i < n) starts[i] = s[threadIdx.x] - v;   // exclusive (block-local)
    if (threadIdx.x == 255) bsum[blockIdx.x] = s[255];
}

// scan2 folded in: each block redundantly prefix-sums bsum[0..blockIdx.x)
__global__ __launch_bounds__(256) void scan3_kernel(int* __restrict__ starts,
                                                    const int* __restrict__ bsum,
                                                    int n, int E, int nb) {
    __shared__ int s[256];
    int t = threadIdx.x;
    s[t] = (t < nb && t < (int)blockIdx.x) ? bsum[t] : 0;
    __syncthreads();
#pragma unroll
    for (int d = 128; d > 0; d >>= 1) {
        if (t < d) s[t] += s[t + d];
        __syncthreads();
    }
    int boff = s[0];
    int i = blockIdx.x * 256 + t;
    if (i < n) starts[i] += boff;
    if (i == n) starts[n] = E;   // sentinel
}

// ---------------------------------------------------------------- CSR scatter (atomic-free)
__global__ void scatter2_kernel(const void* __restrict__ ei, const float* __restrict__ w,
                                const float* __restrict__ dinv, const int* __restrict__ starts,
                                const u32* __restrict__ shoff, const u32* __restrict__ rank,
                                u64* __restrict__ pairs, const int* __restrict__ flag,
                                int E, int N) {
    int i0 = (blockIdx.x * blockDim.x + threadIdx.x) * 4;
    if (i0 >= E) return;
    int f = *flag;
    int r[4], c[4];
#pragma unroll
    for (int k = 0; k < 4; k++) {
        int i = i0 + k;
        if (i < E) { r[k] = load_row_nt(ei, i, E, f); c[k] = load_col_nt(ei, i, E, f); }
    }
#pragma unroll
    for (int k = 0; k < 4; k++) {
        int i = i0 + k;
        if (i < E) {
            float nm = dinv[r[k]] * ntl_f32(&w[i]) * dinv[c[k]];
            u32 rk = ntl_u32(&rank[i]);
            u32 sh = rk >> 28, rks = rk & 0x0fffffffu;
            int pos = starts[c[k]] + (int)shoff[(size_t)sh * N + c[k]] + (int)rks;
            __builtin_nontemporal_store(
                ((u64)__float_as_uint(nm) << 32) | (u32)(r[k] << 7), &pairs[pos]);
        }
    }
}

// ---------------------------------------------------------------- SpMM (CSR gather)
// One wave per node; 32 lanes x 4B per edge, TWO edges per wave-instruction.
// pairs reads are nontemporal (streamed once) so the H table keeps the L2.
__global__ __launch_bounds__(256) void spmm_zr_kernel(
    const unsigned char* __restrict__ H8, const u64* __restrict__ pairs,
    const int* __restrict__ starts, const float* __restrict__ dinv,
    const float* __restrict__ hidden, const float* __restrict__ bz,
    const float* __restrict__ br, float* __restrict__ Z,
    unsigned short* __restrict__ RHb, int N)
{
    int node = (blockIdx.x * 256 + threadIdx.x) >> 6;
    if (node >= N) return;
    const int lane = threadIdx.x & 63;
    const int sub = lane & 31, half = lane >> 5;
    int s = starts[node], e = starts[node + 1];
    float d = dinv[node], d2 = d * d;

    float a0 = 0.f, a1 = 0.f, a2 = 0.f, a3 = 0.f;
    if (half == 0) {   // self-loop term on half 0
        u32 sv = *(const u32*)&H8[(size_t)node * 128 + sub * 4];
        f32x2 s01 = fp8pk<false>(sv), s23 = fp8pk<true>(sv);
        a0 = s01.x * d2; a1 = s01.y * d2; a2 = s23.x * d2; a3 = s23.y * d2;
    }

    int j = s;
    int full = s + ((e - s) & ~15);
    for (; j < full; j += 16) {        // select-free main loop
        u32 hv[8]; float nm[8];
#pragma unroll
        for (int k = 0; k < 8; k++) {
            u64 p = ntl_u64(&pairs[j + k * 2 + half]);
            nm[k] = __uint_as_float((u32)(p >> 32));
            hv[k] = *(const u32*)&H8[(size_t)(u32)p + sub * 4];
        }
#pragma unroll
        for (int k = 0; k < 8; k++) {
            f32x2 h01 = fp8pk<false>(hv[k]), h23 = fp8pk<true>(hv[k]);
            a0 = fmaf(h01.x, nm[k], a0); a1 = fmaf(h01.y, nm[k], a1);
            a2 = fmaf(h23.x, nm[k], a2); a3 = fmaf(h23.y, nm[k], a3);
        }
    }
    if (j < e) {                       // one clamped tail iteration
        u32 hv[8]; float nm[8];
#pragma unroll
        for (int k = 0; k < 8; k++) {
            int jj = j + k * 2 + half;
            u64 p = pairs[(jj < e) ? jj : (e - 1)];
            nm[k] = (jj < e) ? __uint_as_float((u32)(p >> 32)) : 0.f;
            hv[k] = *(const u32*)&H8[(size_t)(u32)p + sub * 4];
        }
#pragma unroll
        for (int k = 0; k < 8; k++) {
            f32x2 h01 = fp8pk<false>(hv[k]), h23 = fp8pk<true>(hv[k]);
            a0 = fmaf(h01.x, nm[k], a0); a1 = fmaf(h01.y, nm[k], a1);
            a2 = fmaf(h23.x, nm[k], a2); a3 = fmaf(h23.y, nm[k], a3);
        }
    }

    a0 += __shfl_xor(a0, 32, 64);
    a1 += __shfl_xor(a1, 32, 64);
    a2 += __shfl_xor(a2, 32, 64);
    a3 += __shfl_xor(a3, 32, 64);

    if (half == 0) {
        if (sub < 16) {                // z channels c = 4*sub .. +3
            int c = sub * 4;
            float4 b4 = *(const float4*)&bz[c];
            float4 o = { sigmoidf_(a0 + b4.x), sigmoidf_(a1 + b4.y),
                         sigmoidf_(a2 + b4.z), sigmoidf_(a3 + b4.w) };
            *(float4*)&Z[(size_t)node * 64 + c] = o;
        } else {                       // r channels c = 4*(sub-16) .. +3
            int c = (sub - 16) * 4;
            float4 b4 = *(const float4*)&br[c];
            float4 hid = *(const float4*)&hidden[(size_t)node * 64 + c];
            float r0 = sigmoidf_(a0 + b4.x) * hid.x;
            float r1 = sigmoidf_(a1 + b4.y) * hid.y;
            float r2 = sigmoidf_(a2 + b4.z) * hid.z;
            float r3 = sigmoidf_(a3 + b4.w) * hid.w;
            ushort4 o = { f2bf(r0), f2bf(r1), f2bf(r2), f2bf(r3) };
            *(ushort4*)&RHb[(size_t)node * 64 + c] = o;
        }
    }
}

__global__ __launch_bounds__(256) void spmm_h_kernel(
    const unsigned short* __restrict__ H, const u64* __restrict__ pairs,
    const int* __restrict__ starts, const float* __restrict__ dinv,
    const float* __restrict__ hidden, const float* __restrict__ bh,
    const float* __restrict__ Z, float* __restrict__ out, int N)
{
    int node = (blockIdx.x * 256 + threadIdx.x) >> 6;
    if (node >= N) return;
    const int lane = threadIdx.x & 63;
    const int sub = lane & 31, half = lane >> 5;
    const unsigned char* Hb = (const unsigned char*)H;
    int s = starts[node], e = starts[node + 1];
    float d = dinv[node], d2 = d * d;

    float ax = 0.f, ay = 0.f;
    if (half == 0) {
        u32 sv = *(const u32*)&Hb[(size_t)node * 128 + sub * 4];
        ax = bflo(sv) * d2; ay = bfhi(sv) * d2;
    }

    int j = s;
    int full = s + ((e - s) & ~15);
    for (; j < full; j += 16) {
        u32 hv[8]; float nm[8];
#pragma unroll
        for (int k = 0; k < 8; k++) {
            u64 p = ntl_u64(&pairs[j + k * 2 + half]);
            nm[k] = __uint_as_float((u32)(p >> 32));
            hv[k] = *(const u32*)&Hb[(size_t)(u32)p + sub * 4];
        }
#pragma unroll
        for (int k = 0; k < 8; k++) {
            ax = fmaf(bflo(hv[k]), nm[k], ax);
            ay = fmaf(bfhi(hv[k]), nm[k], ay);
        }
    }
    if (j < e) {
        u32 hv[8]; float nm[8];
#pragma unroll
        for (int k = 0; k < 8; k++) {
            int jj = j + k * 2 + half;
            u64 p = pairs[(jj < e) ? jj : (e - 1)];
            nm[k] = (jj < e) ? __uint_as_float((u32)(p >> 32)) : 0.f;
            hv[k] = *(const u32*)&Hb[(size_t)(u32)p + sub * 4];
        }
#pragma unroll
        for (int k = 0; k < 8; k++) {
            ax = fmaf(bflo(hv[k]), nm[k], ax);
            ay = fmaf(bfhi(hv[k]), nm[k], ay);
        }
    }

    ax += __shfl_xor(ax, 32, 64);
    ay += __shfl_xor(ay, 32, 64);

    if (half == 0) {                  // channels c = 2*sub, 2*sub+1
        int c = sub * 2;
        size_t idx = (size_t)node * 64 + c;
        float2 hid = *(const float2*)&hidden[idx];
        float2 z   = *(const float2*)&Z[idx];
        float hc0 = tanhf(ax + bh[c]);
        float hc1 = tanhf(ay + bh[c + 1]);
        float2 o = { z.x * hid.x + (1.f - z.x) * hc0,
                     z.y * hid.y + (1.f - z.y) * hc1 };
        *(float2*)&out[idx] = o;
    }
}

// ---------------------------------------------------------------- launcher
extern "C" void kernel_launch(void* const* d_in, const int* in_sizes, int n_in,
                              void* d_out, int out_size, void* d_ws, size_t ws_size,
                              hipStream_t stream) {
    const float* x      = (const float*)d_in[0];
    const void*  eidx   = d_in[1];
    const float* ew     = (const float*)d_in[2];
    const float* hidden = (const float*)d_in[3];
    const float* Wz     = (const float*)d_in[4];
    const float* bz     = (const float*)d_in[5];
    const float* Wr     = (const float*)d_in[6];
    const float* br     = (const float*)d_in[7];
    const float* Wh     = (const float*)d_in[8];
    const float* bh     = (const float*)d_in[9];
    float* out = (float*)d_out;

    const int E = in_sizes[2];            // 800000
    const int N = in_sizes[3] / OUT_CH;   // 50000

    // workspace carve-up (256B aligned)
    char* base = (char*)d_ws;
    size_t off = 0;
    auto carve = [&](size_t bytes) -> char* {
        char* p = base + off;
        off = (off + bytes + 255) & ~(size_t)255;
        return p;
    };
    u64*   packed8 = (u64*) carve((size_t)N * 8 * 8);    // 8 XCD shards
    u32*   shoff   = (u32*) carve((size_t)N * 8 * 4);    // per-shard excl offsets
    u32*   rank    = (u32*) carve((size_t)E * 4);
    float* dinv    = (float*)carve((size_t)N * 4);
    int*   starts  = (int*)  carve((size_t)(N + 1) * 4);
    int*   bsum    = (int*)  carve(256 * 4);
    u64*   pairs   = (u64*)  carve((size_t)E * 8);
    unsigned char*  Hzr8 = (unsigned char*)carve((size_t)N * 128);     // fp8 e4m3 [N][128]
    unsigned short* RHb  = (unsigned short*)carve((size_t)N * 64 * 2); // bf16 [N][64]
    unsigned short* Hhb  = (unsigned short*)carve((size_t)N * 64 * 2); // bf16 [N][64]
    float* Hh32 = (float*)carve((size_t)N * 64 * 4);                   // fp32 partial
    float* Z    = (float*)carve((size_t)N * 64 * 4);
    unsigned short* Bzrt = (unsigned short*)carve((size_t)128 * CAT_CH * 2);
    unsigned short* Wht  = (unsigned short*)carve((size_t)64 * CAT_CH * 2);
    int* flag = (int*)carve(4);
    if (off > ws_size) return;

    const int B256 = 256;
    const int gE4 = (E + 1023) / 1024;        // 4 edges/thread (hist + scatter)
    const int gN = (N + B256 - 1) / B256;     // scan blocking (<=256 blocks)
    const int gM = (N + 127) / 128;           // GEMM row tiles
    const int gW = (N + 3) / 4;               // one wave per node
    const int n16 = N * 4;                    // packed8 bytes / 16
    const int gZ = (n16 + B256 - 1) / B256;
    const int gP = (192 * CAT_CH + 255) / 256;

    // 1. fused prep: zero packed8 + dtype detect + weight pack
    hipLaunchKernelGGL(prep_kernel, dim3(gZ + 1 + gP), dim3(B256), 0, stream,
                       (int4*)packed8, n16, (const unsigned int*)eidx, flag,
                       Wz, Wr, Wh, Bzrt, Wht, gZ);

    // 2. fused work1: GEMM1 + GEMM2a + XCD-local histogram (role-interleaved)
    hipLaunchKernelGGL(work1_kernel, dim3(2 * gM + gE4), dim3(B256), 0, stream,
                       x, hidden, Bzrt, Wht, Hzr8, Hh32,
                       eidx, ew, packed8, rank, flag, E, N, gM);

    // 3. shard merge + exclusive scan -> starts (scan2 folded into scan3)
    hipLaunchKernelGGL(scan1_kernel, dim3(gN), dim3(B256), 0, stream,
                       packed8, dinv, shoff, starts, bsum, N);
    hipLaunchKernelGGL(scan3_kernel, dim3(gN), dim3(B256), 0, stream,
                       starts, bsum, N, E, gN);

    // 4. atomic-free CSR scatter (128B-row byte offsets)
    hipLaunchKernelGGL(scatter2_kernel, dim3(gE4), dim3(B256), 0, stream,
                       eidx, ew, dinv, starts, shoff, rank, pairs, flag, E, N);

    // 5. z/r aggregation (fp8 gather, 2 edges/instr) -> Z, RHb
    hipLaunchKernelGGL(spmm_zr_kernel, dim3(gW), dim3(B256), 0, stream,
                       Hzr8, pairs, starts, dinv, hidden, bz, br, Z, RHb, N);

    // 6. GEMM2b: Hhb = bf16(Hh32 + RHb @ Wh_bot)
    hipLaunchKernelGGL(gemm2b_kernel, dim3(gM), dim3(B256), 0, stream,
                       RHb, Wht, Hh32, Hhb, N);

    // 7. h-candidate aggregation (2 edges/instr) + tanh/GRU blend -> out
    hipLaunchKernelGGL(spmm_h_kernel, dim3(gW), dim3(B256), 0, stream,
                       Hhb, pairs, starts, dinv, hidden, bh, Z, out, N);
}

// Round 18
// 162.310 us; speedup vs baseline: 1.2619x; 1.2619x over previous
//
#include <hip/hip_runtime.h>
#include <hip/hip_bf16.h>
#include <cstdint>
#include <cstddef>

// ---------------------------------------------------------------- constants
#define IN_CH   128
#define OUT_CH  64
#define CAT_CH  192   // IN_CH + OUT_CH
#define ALD     56    // As row stride (ushorts): 112B = 7x16B
#define BLD     40    // Bs row stride (ushorts): 80B = 5x16B

typedef short bf16x8 __attribute__((ext_vector_type(8)));
typedef float f32x4  __attribute__((ext_vector_type(4)));
typedef float f32x2  __attribute__((ext_vector_type(2)));
typedef unsigned long long u64;
typedef unsigned int u32;

__device__ __forceinline__ float sigmoidf_(float x) { return 1.f / (1.f + __expf(-x)); }

// fp32 -> bf16 (RNE)
__device__ __forceinline__ unsigned short f2bf(float f) {
    u32 u = __float_as_uint(f);
    u32 r = (u + 0x7fffu + ((u >> 16) & 1u)) >> 16;
    return (unsigned short)r;
}
__device__ __forceinline__ u32 pk2bf(float a, float b) {
    return (u32)f2bf(a) | ((u32)f2bf(b) << 16);
}
__device__ __forceinline__ float bflo(u32 v) { return __uint_as_float(v << 16); }
__device__ __forceinline__ float bfhi(u32 v) { return __uint_as_float(v & 0xffff0000u); }

// fp8 OCP e4m3 (gfx950 native converts)
__device__ __forceinline__ unsigned char f2e4m3(float f) {
    u32 p = __builtin_amdgcn_cvt_pk_fp8_f32(f, f, 0, false);
    return (unsigned char)p;
}
template <bool HI>
__device__ __forceinline__ f32x2 fp8pk(u32 v) {
    return __builtin_amdgcn_cvt_pk_f32_fp8((int)v, HI);
}

// physical XCD id of the executing wave (gfx940+: HW_REG_XCC_ID, 0..7)
__device__ __forceinline__ u32 xcc_id() {
    u32 v;
    asm("s_getreg_b32 %0, hwreg(HW_REG_XCC_ID)" : "=s"(v));
    return v & 7u;
}

__device__ __forceinline__ int load_col(const void* ei, int i, int E, int f) {
    return f ? ((const int*)ei)[E + i] : (int)((const long long*)ei)[E + i];
}
__device__ __forceinline__ int load_row(const void* ei, int i, int E, int f) {
    return f ? ((const int*)ei)[i] : (int)((const long long*)ei)[i];
}

// ---------------------------------------------------------------- prep (fused)
__global__ void prep_kernel(int4* __restrict__ zdst, int n16,
                            const unsigned int* __restrict__ ei, int* __restrict__ flag,
                            const float* __restrict__ Wz, const float* __restrict__ Wr,
                            const float* __restrict__ Wh,
                            unsigned short* __restrict__ Bzrt, unsigned short* __restrict__ Wht,
                            int gZ) {
    int b = blockIdx.x, t = threadIdx.x;
    if (b < gZ) {
        int i = b * 256 + t;
        if (i < n16) zdst[i] = make_int4(0, 0, 0, 0);
    } else if (b == gZ) {
        if (t < 64) {
            unsigned int v = ei[(t << 1) + 1];
            unsigned long long bl = __ballot(v != 0u);
            if (t == 0) *flag = (bl != 0ull) ? 1 : 0;   // 1 => int32 layout
        }
    } else {
        int i = (b - gZ - 1) * 256 + t;
        if (i < 192 * CAT_CH) {
            int col = i / CAT_CH, k = i % CAT_CH;
            if (col < 128) {
                float v = (col < 64) ? Wz[k * 64 + col] : Wr[k * 64 + (col - 64)];
                Bzrt[col * CAT_CH + k] = f2bf(v);
            } else {
                Wht[(col - 128) * CAT_CH + k] = f2bf(Wh[k * 64 + (col - 128)]);
            }
        }
    }
}

// ---------------------------------------------------------------- GEMM body (device)
// C[128 rows][TN] = [A0(fp32)|A1] tile @ Bt[col][bOff..bOff+K), k-major bf16.
// B staged per-32-k step into Bs[TN][BLD] under the same barriers as A.
// OUT: 0=bf16, 1=fp8 e4m3, 2=fp32.  Cacc: optional fp32 addend (row-major TN).
template <int TN, int OUT, bool A1F32>
__device__ __forceinline__ void gemm_body(
    unsigned short* __restrict__ As /*[128][ALD]*/,
    unsigned short* __restrict__ Bs /*[TN][BLD]*/,
    int blk, const float* __restrict__ A0, int a0w,
    const void* __restrict__ A1, int a1w,
    const unsigned short* __restrict__ Bt, int bOff, int K,
    const float* __restrict__ Cacc, void* __restrict__ Cout, int nrows)
{
    const int t = threadIdx.x, lane = t & 63, wave = t >> 6;
    const int rowBase = blk * 128;

    f32x4 acc[2][TN / 16];
#pragma unroll
    for (int rf = 0; rf < 2; rf++)
#pragma unroll
        for (int cf = 0; cf < TN / 16; cf++) acc[rf][cf] = (f32x4){0.f, 0.f, 0.f, 0.f};

    const int srow = t >> 1, half = t & 1;     // A staging: 2 threads/row, 16 k each
    int arow = rowBase + srow;
    if (arow >= nrows) arow = nrows - 1;

    for (int k0 = 0; k0 < K; k0 += 32) {
        __syncthreads();
        {   // stage A chunk (128 rows x 32 k)
            int kk = k0 + half * 16;           // 16-aligned; never straddles a0w
            u32 pk[8];
            if (kk < a0w) {                    // A0: fp32 -> bf16 on the fly
                const float* src = A0 + (size_t)arow * a0w + kk;
#pragma unroll
                for (int q = 0; q < 4; q++) {
                    float4 v = *(const float4*)(src + q * 4);
                    pk[q * 2]     = pk2bf(v.x, v.y);
                    pk[q * 2 + 1] = pk2bf(v.z, v.w);
                }
            } else if (A1F32) {
                const float* src = (const float*)A1 + (size_t)arow * a1w + (kk - a0w);
#pragma unroll
                for (int q = 0; q < 4; q++) {
                    float4 v = *(const float4*)(src + q * 4);
                    pk[q * 2]     = pk2bf(v.x, v.y);
                    pk[q * 2 + 1] = pk2bf(v.z, v.w);
                }
            } else {                           // A1 already bf16
                const unsigned short* src =
                    (const unsigned short*)A1 + (size_t)arow * a1w + (kk - a0w);
                int4 v0 = *(const int4*)src;
                int4 v1 = *(const int4*)(src + 8);
                pk[0] = v0.x; pk[1] = v0.y; pk[2] = v0.z; pk[3] = v0.w;
                pk[4] = v1.x; pk[5] = v1.y; pk[6] = v1.z; pk[7] = v1.w;
            }
            *(int4*)&As[srow * ALD + half * 16]     = make_int4(pk[0], pk[1], pk[2], pk[3]);
            *(int4*)&As[srow * ALD + half * 16 + 8] = make_int4(pk[4], pk[5], pk[6], pk[7]);
        }
        // stage B tile (TN cols x 32 k), 16B chunks
#pragma unroll
        for (int idx = t * 8; idx < TN * 32; idx += 256 * 8) {
            int col = idx >> 5, kk = idx & 31;
            *(int4*)&Bs[col * BLD + kk] =
                *(const int4*)&Bt[(size_t)col * CAT_CH + bOff + k0 + kk];
        }
        __syncthreads();

        const int rbase = wave * 32;
        const int koff = (lane >> 4) * 8;
        bf16x8 a0 = *(const bf16x8*)&As[(rbase + (lane & 15)) * ALD + koff];
        bf16x8 a1 = *(const bf16x8*)&As[(rbase + 16 + (lane & 15)) * ALD + koff];
#pragma unroll
        for (int cf = 0; cf < TN / 16; cf++) {
            bf16x8 b = *(const bf16x8*)&Bs[(cf * 16 + (lane & 15)) * BLD + koff];
            acc[0][cf] = __builtin_amdgcn_mfma_f32_16x16x32_bf16(a0, b, acc[0][cf], 0, 0, 0);
            acc[1][cf] = __builtin_amdgcn_mfma_f32_16x16x32_bf16(a1, b, acc[1][cf], 0, 0, 0);
        }
    }

#pragma unroll
    for (int rf = 0; rf < 2; rf++)
#pragma unroll
        for (int cf = 0; cf < TN / 16; cf++) {
            int row0 = rowBase + wave * 32 + rf * 16 + (lane >> 4) * 4;
            int col  = cf * 16 + (lane & 15);
#pragma unroll
            for (int r = 0; r < 4; r++) {
                int row = row0 + r;
                if (row < nrows) {
                    float v = acc[rf][cf][r];
                    if (Cacc) v += Cacc[(size_t)row * TN + col];
                    if (OUT == 1)
                        ((unsigned char*)Cout)[(size_t)row * TN + col] = f2e4m3(v);
                    else if (OUT == 2)
                        ((float*)Cout)[(size_t)row * TN + col] = v;
                    else
                        ((unsigned short*)Cout)[(size_t)row * TN + col] = f2bf(v);
                }
            }
        }
}

// ---------------------------------------------------------------- work1 (fused)
// Role-interleaved: for blk < 3*gM, role = blk%3 (0: GEMM1, 1: GEMM2a, 2: hist);
// beyond, all hist. Hist shards by PHYSICAL XCD (HW_REG_XCC_ID) with
// workgroup-scope atomics (execute in the local XCD L2). Sound because every
// writer of shard s is, by definition, on XCD s; kernel-end writeback
// publishes to scan1.
__global__ __launch_bounds__(256) void work1_kernel(
    const float* __restrict__ x, const float* __restrict__ hidden,
    const unsigned short* __restrict__ Bzrt, const unsigned short* __restrict__ Wht,
    unsigned char* __restrict__ Hzr8, float* __restrict__ Hh32,
    const void* __restrict__ ei, const float* __restrict__ ew,
    u64* __restrict__ packed8, u32* __restrict__ rank,
    const int* __restrict__ flag, int E, int N, int gM)
{
    __shared__ unsigned short As[128 * ALD];
    __shared__ unsigned short Bs[128 * BLD];

    const int blk = blockIdx.x;
    int role, idx;
    if (blk < 3 * gM) { role = blk % 3; idx = blk / 3; }
    else              { role = 2;       idx = gM + (blk - 3 * gM); }

    if (role == 0) {
        // GEMM1: Hzr8(fp8) = [x|hidden] @ Bzrt, K=192
        gemm_body<128, 1, true>(As, Bs, idx, x, 128, (const void*)hidden, 64,
                                Bzrt, 0, 192, nullptr, (void*)Hzr8, N);
    } else if (role == 1) {
        // GEMM2a: Hh32(fp32) = x @ Wht[:, 0:128), K=128
        gemm_body<64, 2, false>(As, Bs, idx, x, 128, nullptr, 0,
                                Wht, 0, 128, nullptr, (void*)Hh32, N);
    } else {
        // hist: XCD-local packed histogram, 4 edges/thread
        int i0 = (idx * 256 + threadIdx.x) * 4;
        if (i0 >= E) return;
        const u32 shard = xcc_id();
        u64* __restrict__ shp = packed8 + (size_t)shard * N;
        int f = *flag;
        u32 rk[4];
#pragma unroll
        for (int k = 0; k < 4; k++) {
            int i = i0 + k;
            if (i < E) {
                int c = load_col(ei, i, E, f);
                u32 wq = __float2uint_rn(ew[i] * 1048576.0f);   // 2^20 scale
                u64 old = __hip_atomic_fetch_add(&shp[c], (1ull << 32) | (u64)wq,
                                                 __ATOMIC_RELAXED,
                                                 __HIP_MEMORY_SCOPE_WORKGROUP);
                rk[k] = (shard << 28) | (u32)(old >> 32);
            }
        }
#pragma unroll
        for (int k = 0; k < 4; k++)
            if (i0 + k < E) rank[i0 + k] = rk[k];
    }
}

// ---------------------------------------------------------------- GEMM2b
// Hhb(bf16) = bf16( Hh32 + RHb @ Wht[:, 128:192) ), K=64
__global__ __launch_bounds__(256) void gemm2b_kernel(
    const unsigned short* __restrict__ RHb, const unsigned short* __restrict__ Wht,
    const float* __restrict__ Hh32, unsigned short* __restrict__ Hhb, int N)
{
    __shared__ unsigned short As[128 * ALD];
    __shared__ unsigned short Bs[64 * BLD];
    gemm_body<64, 0, false>(As, Bs, blockIdx.x, nullptr, 0, (const void*)RHb, 64,
                            Wht, 128, 64, Hh32, (void*)Hhb, N);
}

// ---------------------------------------------------------------- scan (2-phase)
__global__ __launch_bounds__(256) void scan1_kernel(const u64* __restrict__ packed8,
                                                    float* __restrict__ dinv,
                                                    u32* __restrict__ shoff,
                                                    int* __restrict__ starts,
                                                    int* __restrict__ bsum, int n) {
    __shared__ int s[256];
    int i = blockIdx.x * 256 + threadIdx.x;
    int v = 0;
    if (i < n) {
        u32 run = 0, wsum = 0;
#pragma unroll
        for (int sh = 0; sh < 8; sh++) {
            u64 p = packed8[(size_t)sh * n + i];
            shoff[(size_t)sh * n + i] = run;
            run  += (u32)(p >> 32);
            wsum += (u32)p;
        }
        float ws = (float)wsum * (1.0f / 1048576.0f);
        dinv[i] = rsqrtf(1.0f + ws);                 // self-loop weight 1 => deg >= 1
        v = (int)run;
    }
    s[threadIdx.x] = v;
    __syncthreads();
#pragma unroll
    for (int d = 1; d < 256; d <<= 1) {
        int t = (threadIdx.x >= d) ? s[threadIdx.x - d] : 0;
        __syncthreads();
        s[threadIdx.x] += t;
        __syncthreads();
    }
    if (i < n) starts[i] = s[threadIdx.x] - v;   // exclusive (block-local)
    if (threadIdx.x == 255) bsum[blockIdx.x] = s[255];
}

// scan2 folded in: each block redundantly prefix-sums bsum[0..blockIdx.x)
__global__ __launch_bounds__(256) void scan3_kernel(int* __restrict__ starts,
                                                    const int* __restrict__ bsum,
                                                    int n, int E, int nb) {
    __shared__ int s[256];
    int t = threadIdx.x;
    s[t] = (t < nb && t < (int)blockIdx.x) ? bsum[t] : 0;
    __syncthreads();
#pragma unroll
    for (int d = 128; d > 0; d >>= 1) {
        if (t < d) s[t] += s[t + d];
        __syncthreads();
    }
    int boff = s[0];
    int i = blockIdx.x * 256 + t;
    if (i < n) starts[i] += boff;
    if (i == n) starts[n] = E;   // sentinel
}

// ---------------------------------------------------------------- CSR scatter (atomic-free)
__global__ void scatter2_kernel(const void* __restrict__ ei, const float* __restrict__ w,
                                const float* __restrict__ dinv, const int* __restrict__ starts,
                                const u32* __restrict__ shoff, const u32* __restrict__ rank,
                                u64* __restrict__ pairs, const int* __restrict__ flag,
                                int E, int N) {
    int i0 = (blockIdx.x * blockDim.x + threadIdx.x) * 4;
    if (i0 >= E) return;
    int f = *flag;
    int r[4], c[4];
#pragma unroll
    for (int k = 0; k < 4; k++) {
        int i = i0 + k;
        if (i < E) { r[k] = load_row(ei, i, E, f); c[k] = load_col(ei, i, E, f); }
    }
#pragma unroll
    for (int k = 0; k < 4; k++) {
        int i = i0 + k;
        if (i < E) {
            float nm = dinv[r[k]] * w[i] * dinv[c[k]];
            u32 rk = rank[i];
            u32 sh = rk >> 28, rks = rk & 0x0fffffffu;
            int pos = starts[c[k]] + (int)shoff[(size_t)sh * N + c[k]] + (int)rks;
            pairs[pos] = ((u64)__float_as_uint(nm) << 32) | (u32)(r[k] << 7);
        }
    }
}

// ---------------------------------------------------------------- SpMM (CSR gather)
// One wave per node; 32 lanes x 4B per edge, TWO edges per wave-instruction.
__global__ __launch_bounds__(256) void spmm_zr_kernel(
    const unsigned char* __restrict__ H8, const u64* __restrict__ pairs,
    const int* __restrict__ starts, const float* __restrict__ dinv,
    const float* __restrict__ hidden, const float* __restrict__ bz,
    const float* __restrict__ br, float* __restrict__ Z,
    unsigned short* __restrict__ RHb, int N)
{
    int node = (blockIdx.x * 256 + threadIdx.x) >> 6;
    if (node >= N) return;
    const int lane = threadIdx.x & 63;
    const int sub = lane & 31, half = lane >> 5;
    int s = starts[node], e = starts[node + 1];
    float d = dinv[node], d2 = d * d;

    float a0 = 0.f, a1 = 0.f, a2 = 0.f, a3 = 0.f;
    if (half == 0) {   // self-loop term on half 0
        u32 sv = *(const u32*)&H8[(size_t)node * 128 + sub * 4];
        f32x2 s01 = fp8pk<false>(sv), s23 = fp8pk<true>(sv);
        a0 = s01.x * d2; a1 = s01.y * d2; a2 = s23.x * d2; a3 = s23.y * d2;
    }

    int j = s;
    int full = s + ((e - s) & ~15);
    for (; j < full; j += 16) {        // select-free main loop
        u32 hv[8]; float nm[8];
#pragma unroll
        for (int k = 0; k < 8; k++) {
            u64 p = pairs[j + k * 2 + half];
            nm[k] = __uint_as_float((u32)(p >> 32));
            hv[k] = *(const u32*)&H8[(size_t)(u32)p + sub * 4];
        }
#pragma unroll
        for (int k = 0; k < 8; k++) {
            f32x2 h01 = fp8pk<false>(hv[k]), h23 = fp8pk<true>(hv[k]);
            a0 = fmaf(h01.x, nm[k], a0); a1 = fmaf(h01.y, nm[k], a1);
            a2 = fmaf(h23.x, nm[k], a2); a3 = fmaf(h23.y, nm[k], a3);
        }
    }
    if (j < e) {                       // one clamped tail iteration
        u32 hv[8]; float nm[8];
#pragma unroll
        for (int k = 0; k < 8; k++) {
            int jj = j + k * 2 + half;
            u64 p = pairs[(jj < e) ? jj : (e - 1)];
            nm[k] = (jj < e) ? __uint_as_float((u32)(p >> 32)) : 0.f;
            hv[k] = *(const u32*)&H8[(size_t)(u32)p + sub * 4];
        }
#pragma unroll
        for (int k = 0; k < 8; k++) {
            f32x2 h01 = fp8pk<false>(hv[k]), h23 = fp8pk<true>(hv[k]);
            a0 = fmaf(h01.x, nm[k], a0); a1 = fmaf(h01.y, nm[k], a1);
            a2 = fmaf(h23.x, nm[k], a2); a3 = fmaf(h23.y, nm[k], a3);
        }
    }

    a0 += __shfl_xor(a0, 32, 64);
    a1 += __shfl_xor(a1, 32, 64);
    a2 += __shfl_xor(a2, 32, 64);
    a3 += __shfl_xor(a3, 32, 64);

    if (half == 0) {
        if (sub < 16) {                // z channels c = 4*sub .. +3
            int c = sub * 4;
            float4 b4 = *(const float4*)&bz[c];
            float4 o = { sigmoidf_(a0 + b4.x), sigmoidf_(a1 + b4.y),
                         sigmoidf_(a2 + b4.z), sigmoidf_(a3 + b4.w) };
            *(float4*)&Z[(size_t)node * 64 + c] = o;
        } else {                       // r channels c = 4*(sub-16) .. +3
            int c = (sub - 16) * 4;
            float4 b4 = *(const float4*)&br[c];
            float4 hid = *(const float4*)&hidden[(size_t)node * 64 + c];
            float r0 = sigmoidf_(a0 + b4.x) * hid.x;
            float r1 = sigmoidf_(a1 + b4.y) * hid.y;
            float r2 = sigmoidf_(a2 + b4.z) * hid.z;
            float r3 = sigmoidf_(a3 + b4.w) * hid.w;
            ushort4 o = { f2bf(r0), f2bf(r1), f2bf(r2), f2bf(r3) };
            *(ushort4*)&RHb[(size_t)node * 64 + c] = o;
        }
    }
}

__global__ __launch_bounds__(256) void spmm_h_kernel(
    const unsigned short* __restrict__ H, const u64* __restrict__ pairs,
    const int* __restrict__ starts, const float* __restrict__ dinv,
    const float* __restrict__ hidden, const float* __restrict__ bh,
    const float* __restrict__ Z, float* __restrict__ out, int N)
{
    int node = (blockIdx.x * 256 + threadIdx.x) >> 6;
    if (node >= N) return;
    const int lane = threadIdx.x & 63;
    const int sub = lane & 31, half = lane >> 5;
    const unsigned char* Hb = (const unsigned char*)H;
    int s = starts[node], e = starts[node + 1];
    float d = dinv[node], d2 = d * d;

    float ax = 0.f, ay = 0.f;
    if (half == 0) {
        u32 sv = *(const u32*)&Hb[(size_t)node * 128 + sub * 4];
        ax = bflo(sv) * d2; ay = bfhi(sv) * d2;
    }

    int j = s;
    int full = s + ((e - s) & ~15);
    for (; j < full; j += 16) {
        u32 hv[8]; float nm[8];
#pragma unroll
        for (int k = 0; k < 8; k++) {
            u64 p = pairs[j + k * 2 + half];
            nm[k] = __uint_as_float((u32)(p >> 32));
            hv[k] = *(const u32*)&Hb[(size_t)(u32)p + sub * 4];
        }
#pragma unroll
        for (int k = 0; k < 8; k++) {
            ax = fmaf(bflo(hv[k]), nm[k], ax);
            ay = fmaf(bfhi(hv[k]), nm[k], ay);
        }
    }
    if (j < e) {
        u32 hv[8]; float nm[8];
#pragma unroll
        for (int k = 0; k < 8; k++) {
            int jj = j + k * 2 + half;
            u64 p = pairs[(jj < e) ? jj : (e - 1)];
            nm[k] = (jj < e) ? __uint_as_float((u32)(p >> 32)) : 0.f;
            hv[k] = *(const u32*)&Hb[(size_t)(u32)p + sub * 4];
        }
#pragma unroll
        for (int k = 0; k < 8; k++) {
            ax = fmaf(bflo(hv[k]), nm[k], ax);
            ay = fmaf(bfhi(hv[k]), nm[k], ay);
        }
    }

    ax += __shfl_xor(ax, 32, 64);
    ay += __shfl_xor(ay, 32, 64);

    if (half == 0) {                  // channels c = 2*sub, 2*sub+1
        int c = sub * 2;
        size_t idx = (size_t)node * 64 + c;
        float2 hid = *(const float2*)&hidden[idx];
        float2 z   = *(const float2*)&Z[idx];
        float hc0 = tanhf(ax + bh[c]);
        float hc1 = tanhf(ay + bh[c + 1]);
        float2 o = { z.x * hid.x + (1.f - z.x) * hc0,
                     z.y * hid.y + (1.f - z.y) * hc1 };
        *(float2*)&out[idx] = o;
    }
}

// ---------------------------------------------------------------- launcher
extern "C" void kernel_launch(void* const* d_in, const int* in_sizes, int n_in,
                              void* d_out, int out_size, void* d_ws, size_t ws_size,
                              hipStream_t stream) {
    const float* x      = (const float*)d_in[0];
    const void*  eidx   = d_in[1];
    const float* ew     = (const float*)d_in[2];
    const float* hidden = (const float*)d_in[3];
    const float* Wz     = (const float*)d_in[4];
    const float* bz     = (const float*)d_in[5];
    const float* Wr     = (const float*)d_in[6];
    const float* br     = (const float*)d_in[7];
    const float* Wh     = (const float*)d_in[8];
    const float* bh     = (const float*)d_in[9];
    float* out = (float*)d_out;

    const int E = in_sizes[2];            // 800000
    const int N = in_sizes[3] / OUT_CH;   // 50000

    // workspace carve-up (256B aligned)
    char* base = (char*)d_ws;
    size_t off = 0;
    auto carve = [&](size_t bytes) -> char* {
        char* p = base + off;
        off = (off + bytes + 255) & ~(size_t)255;
        return p;
    };
    u64*   packed8 = (u64*) carve((size_t)N * 8 * 8);    // 8 XCD shards
    u32*   shoff   = (u32*) carve((size_t)N * 8 * 4);    // per-shard excl offsets
    u32*   rank    = (u32*) carve((size_t)E * 4);
    float* dinv    = (float*)carve((size_t)N * 4);
    int*   starts  = (int*)  carve((size_t)(N + 1) * 4);
    int*   bsum    = (int*)  carve(256 * 4);
    u64*   pairs   = (u64*)  carve((size_t)E * 8);
    unsigned char*  Hzr8 = (unsigned char*)carve((size_t)N * 128);     // fp8 e4m3 [N][128]
    unsigned short* RHb  = (unsigned short*)carve((size_t)N * 64 * 2); // bf16 [N][64]
    unsigned short* Hhb  = (unsigned short*)carve((size_t)N * 64 * 2); // bf16 [N][64]
    float* Hh32 = (float*)carve((size_t)N * 64 * 4);                   // fp32 partial
    float* Z    = (float*)carve((size_t)N * 64 * 4);
    unsigned short* Bzrt = (unsigned short*)carve((size_t)128 * CAT_CH * 2);
    unsigned short* Wht  = (unsigned short*)carve((size_t)64 * CAT_CH * 2);
    int* flag = (int*)carve(4);
    if (off > ws_size) return;

    const int B256 = 256;
    const int gE4 = (E + 1023) / 1024;        // 4 edges/thread (hist + scatter)
    const int gN = (N + B256 - 1) / B256;     // scan blocking (<=256 blocks)
    const int gM = (N + 127) / 128;           // GEMM row tiles
    const int gW = (N + 3) / 4;               // one wave per node
    const int n16 = N * 4;                    // packed8 bytes / 16
    const int gZ = (n16 + B256 - 1) / B256;
    const int gP = (192 * CAT_CH + 255) / 256;

    // 1. fused prep: zero packed8 + dtype detect + weight pack
    hipLaunchKernelGGL(prep_kernel, dim3(gZ + 1 + gP), dim3(B256), 0, stream,
                       (int4*)packed8, n16, (const unsigned int*)eidx, flag,
                       Wz, Wr, Wh, Bzrt, Wht, gZ);

    // 2. fused work1: GEMM1 + GEMM2a + XCD-local histogram (role-interleaved)
    hipLaunchKernelGGL(work1_kernel, dim3(2 * gM + gE4), dim3(B256), 0, stream,
                       x, hidden, Bzrt, Wht, Hzr8, Hh32,
                       eidx, ew, packed8, rank, flag, E, N, gM);

    // 3. shard merge + exclusive scan -> starts (scan2 folded into scan3)
    hipLaunchKernelGGL(scan1_kernel, dim3(gN), dim3(B256), 0, stream,
                       packed8, dinv, shoff, starts, bsum, N);
    hipLaunchKernelGGL(scan3_kernel, dim3(gN), dim3(B256), 0, stream,
                       starts, bsum, N, E, gN);

    // 4. atomic-free CSR scatter (128B-row byte offsets)
    hipLaunchKernelGGL(scatter2_kernel, dim3(gE4), dim3(B256), 0, stream,
                       eidx, ew, dinv, starts, shoff, rank, pairs, flag, E, N);

    // 5. z/r aggregation (fp8 gather, 2 edges/instr) -> Z, RHb
    hipLaunchKernelGGL(spmm_zr_kernel, dim3(gW), dim3(B256), 0, stream,
                       Hzr8, pairs, starts, dinv, hidden, bz, br, Z, RHb, N);

    // 6. GEMM2b: Hhb = bf16(Hh32 + RHb @ Wh_bot)
    hipLaunchKernelGGL(gemm2b_kernel, dim3(gM), dim3(B256), 0, stream,
                       RHb, Wht, Hh32, Hhb, N);

    // 7. h-candidate aggregation (2 edges/instr) + tanh/GRU blend -> out
    hipLaunchKernelGGL(spmm_h_kernel, dim3(gW), dim3(B256), 0, stream,
                       Hhb, pairs, starts, dinv, hidden, bh, Z, out, N);
}